// Round 5
// baseline (49.923 us; speedup 1.0000x reference)
//
#include <hip/hip_runtime.h>

#define HW   4096
#define CIN  32
// scale in log2 domain: (1/sqrt(NCLASS)) * log2(e); NCLASS = 2
#define SCALE2 (0.70710678118654752f * 1.44269504088896340f)

// Raw v_exp_f32 (2^x): args bounded (|x| <~ 12), skip libm denormal fixup.
__device__ __forceinline__ float exp2_raw(float x) {
#if __has_builtin(__builtin_amdgcn_exp2f)
    return __builtin_amdgcn_exp2f(x);
#else
    float r;
    asm("v_exp_f32 %0, %1" : "=v"(r) : "v"(x));
    return r;
#endif
}

// ---------------- Kernel A: f2 = W2*x + b2 only (f1 is recomputed inside B)
__global__ __launch_bounds__(256) void proj2_kernel(
        const float* __restrict__ feat,
        const float* __restrict__ w2, const float* __restrict__ b2,
        float2* __restrict__ f2v) {
    __shared__ float2 red[4][64];
    int tid = threadIdx.x;
    int pl = tid & 63;
    int cq = tid >> 6;                 // wave id = channel quarter (8 ch each)
    int b = blockIdx.x;                // 256 blocks
    int n = b >> 6;
    int p = ((b & 63) << 6) + pl;
    const float* fbase = feat + ((size_t)n * CIN + cq * 8) * HW + p;
    float a0 = 0.f, a1 = 0.f;
#pragma unroll
    for (int c = 0; c < 8; ++c) {
        float v = fbase[(size_t)c * HW];
        a0 += v * w2[cq * 8 + c];
        a1 += v * w2[CIN + cq * 8 + c];
    }
    red[cq][pl] = make_float2(a0, a1);
    __syncthreads();
    if (tid < 64) {
        float2 r0 = red[0][tid], r1 = red[1][tid], r2 = red[2][tid], r3 = red[3][tid];
        int idx = n * HW + ((b & 63) << 6) + tid;
        f2v[idx] = make_float2(r0.x + r1.x + r2.x + r3.x + b2[0],
                               r0.y + r1.y + r2.y + r3.y + b2[1]);
    }
}

// ---------------- Kernel B: l[p] = sum_q 2^(f1[p].f2[q]*s); write {f1*s, V0/l, V1/l}
// block = (n, 64 p's); lane = p; wave wid streams q-slice [wid*512,+512) of f2
// at wave-uniform addresses (-> s_load scalar stream).
__global__ __launch_bounds__(512) void rowstats_kernel(
        const float* __restrict__ feat,
        const float* __restrict__ w1, const float* __restrict__ b1,
        const float2* __restrict__ f2v, const float* __restrict__ outv,
        float4* __restrict__ stats4) {
    __shared__ float redA[8][64];
    __shared__ float redB[8][64];
    __shared__ float2 sf[64];
    int tid = threadIdx.x;
    int pl = tid & 63;
    int grp = tid >> 6;                // 8 waves
    int b = blockIdx.x;                // 256 blocks
    int n = b >> 6;
    int pg = (b & 63) << 6;
    int p = pg + pl;
    int base = n * HW;

    // recompute f1 for this block's 64 p's: wave grp covers channels grp*4..+4
    {
        const float* fb = feat + ((size_t)n * CIN + grp * 4) * HW + p;
        float s0 = 0.f, s1 = 0.f;
#pragma unroll
        for (int c = 0; c < 4; ++c) {
            float v = fb[(size_t)c * HW];
            s0 += v * w1[grp * 4 + c];
            s1 += v * w1[CIN + grp * 4 + c];
        }
        redA[grp][pl] = s0;
        redB[grp][pl] = s1;
    }
    __syncthreads();
    if (tid < 64) {
        float a = b1[0], c = b1[1];
#pragma unroll
        for (int g = 0; g < 8; ++g) { a += redA[g][tid]; c += redB[g][tid]; }
        sf[tid] = make_float2(a * SCALE2, c * SCALE2);
    }
    __syncthreads();
    float f10 = sf[pl].x, f11 = sf[pl].y;

    int wid = __builtin_amdgcn_readfirstlane(grp);
    const float4* f2b = (const float4*)(f2v + base) + wid * 256;  // 2 q per entry
    float a0 = 0.f, a1 = 0.f, a2 = 0.f, a3 = 0.f;
#pragma unroll 4
    for (int s = 0; s < 256; s += 2) {
        float4 u = f2b[s];             // uniform -> s_load_dwordx4/x8
        float4 v = f2b[s + 1];
        a0 += exp2_raw(f10 * u.x + f11 * u.y);
        a1 += exp2_raw(f10 * u.z + f11 * u.w);
        a2 += exp2_raw(f10 * v.x + f11 * v.y);
        a3 += exp2_raw(f10 * v.z + f11 * v.w);
    }
    float l = (a0 + a1) + (a2 + a3);
    __syncthreads();                   // redA reuse
    redA[grp][pl] = l;
    __syncthreads();
    if (tid < 64) {
        float lt = 0.f;
#pragma unroll
        for (int g = 0; g < 8; ++g) lt += redA[g][tid];
        float inv = 1.0f / lt;
        int pp = pg + tid;
        float v0 = outv[(n * 2 + 0) * HW + pp];
        float v1 = outv[(n * 2 + 1) * HW + pp];
        float2 f1 = sf[tid];
        stats4[base + pp] = make_float4(f1.x, f1.y, v0 * inv, v1 * inv);
    }
}

// ---------------- Kernel C: o[c,q] = sum_p (V[c,p]/l[p]) * 2^(f1[p].f2[q]*s)
// block = (n, 64 q's); lane = q; wave wid streams p-slice [wid*512,+512) of
// stats4 at wave-uniform addresses (-> s_load scalar stream).
__global__ __launch_bounds__(512) void colout_kernel(
        const float2* __restrict__ f2v, const float4* __restrict__ stats4,
        float* __restrict__ o) {
    __shared__ float red0[8][64];
    __shared__ float red1[8][64];
    int tid = threadIdx.x;
    int ql = tid & 63;
    int grp = tid >> 6;                // 8 waves
    int b = blockIdx.x;                // 256 blocks
    int n = b >> 6;
    int qg = (b & 63) << 6;
    int base = n * HW;

    float2 g = f2v[base + qg + ql];    // per-lane q projection (SCALE2 in stats)

    int wid = __builtin_amdgcn_readfirstlane(grp);
    const float4* stb = stats4 + base + wid * 512;
    float o00 = 0.f, o01 = 0.f, o10 = 0.f, o11 = 0.f;
#pragma unroll 4
    for (int s = 0; s < 512; s += 2) {
        float4 sa = stb[s];            // {f1x*s, f1y*s, V0/l, V1/l} uniform -> s_load
        float4 sb = stb[s + 1];
        float ea = exp2_raw(g.x * sa.x + g.y * sa.y);
        float eb = exp2_raw(g.x * sb.x + g.y * sb.y);
        o00 += sa.z * ea;
        o01 += sa.w * ea;
        o10 += sb.z * eb;
        o11 += sb.w * eb;
    }
    red0[grp][ql] = o00 + o10;
    red1[grp][ql] = o01 + o11;
    __syncthreads();
    if (tid < 128) {
        int qq = tid & 63, ch = tid >> 6;
        float r = 0.f;
        if (ch == 0) {
#pragma unroll
            for (int g2 = 0; g2 < 8; ++g2) r += red0[g2][qq];
        } else {
#pragma unroll
            for (int g2 = 0; g2 < 8; ++g2) r += red1[g2][qq];
        }
        o[(n * 2 + ch) * HW + qg + qq] = r;
    }
}

extern "C" void kernel_launch(void* const* d_in, const int* in_sizes, int n_in,
                              void* d_out, int out_size, void* d_ws, size_t ws_size,
                              hipStream_t stream) {
    const float* feat = (const float*)d_in[0];   // (4,32,64,64)
    const float* outv = (const float*)d_in[1];   // (4,2,64,64)
    const float* w1   = (const float*)d_in[2];   // (2,32)
    const float* b1   = (const float*)d_in[3];   // (2,)
    const float* w2   = (const float*)d_in[4];   // (2,32)
    const float* b2   = (const float*)d_in[5];   // (2,)
    float* o = (float*)d_out;                    // (4,2,64,64)

    // workspace layout:
    float*  ws     = (float*)d_ws;
    float2* f2v    = (float2*)ws;                // 16384 float2 = 128 KB
    float4* stats4 = (float4*)(ws + 32768);      // 16384 float4 = 256 KB

    proj2_kernel<<<256, 256, 0, stream>>>(feat, w2, b2, f2v);
    rowstats_kernel<<<256, 512, 0, stream>>>(feat, w1, b1, f2v, outv, stats4);
    colout_kernel<<<256, 512, 0, stream>>>(f2v, stats4, o);
}

// Round 6
// 35.532 us; speedup vs baseline: 1.4050x; 1.4050x over previous
//
#include <hip/hip_runtime.h>

#define HW   4096
#define CIN  32
// scale in log2 domain: (1/sqrt(NCLASS)) * log2(e); NCLASS = 2
#define SCALE2 (0.70710678118654752f * 1.44269504088896340f)

// Raw v_exp_f32 (2^x): args bounded (|x| <~ 12), skip libm denormal fixup.
__device__ __forceinline__ float exp2_raw(float x) {
#if __has_builtin(__builtin_amdgcn_exp2f)
    return __builtin_amdgcn_exp2f(x);
#else
    float r;
    asm("v_exp_f32 %0, %1" : "=v"(r) : "v"(x));
    return r;
#endif
}

// ---------------- Kernel A: 1x1 conv projections, channel-split 4-way across waves
__global__ __launch_bounds__(256) void proj_kernel(
        const float* __restrict__ feat,
        const float* __restrict__ w1, const float* __restrict__ b1,
        const float* __restrict__ w2, const float* __restrict__ b2,
        float2* __restrict__ f1v, float2* __restrict__ f2v) {
    __shared__ float4 red[4][64];
    int tid = threadIdx.x;
    int pl = tid & 63;
    int cq = tid >> 6;                 // wave id = channel quarter
    int b = blockIdx.x;                // 256 blocks
    int n = b >> 6;
    int p = ((b & 63) << 6) + pl;
    const float* fbase = feat + ((size_t)n * CIN + cq * 8) * HW + p;
    float a10 = 0.f, a11 = 0.f, a20 = 0.f, a21 = 0.f;
#pragma unroll
    for (int c = 0; c < 8; ++c) {
        float v = fbase[(size_t)c * HW];
        a10 += v * w1[cq * 8 + c];
        a11 += v * w1[32 + cq * 8 + c];
        a20 += v * w2[cq * 8 + c];
        a21 += v * w2[32 + cq * 8 + c];
    }
    red[cq][pl] = make_float4(a10, a11, a20, a21);
    __syncthreads();
    if (tid < 64) {
        float4 r0 = red[0][tid], r1 = red[1][tid], r2 = red[2][tid], r3 = red[3][tid];
        int idx = n * HW + ((b & 63) << 6) + tid;
        f1v[idx] = make_float2(r0.x + r1.x + r2.x + r3.x + b1[0],
                               r0.y + r1.y + r2.y + r3.y + b1[1]);
        f2v[idx] = make_float2(r0.z + r1.z + r2.z + r3.z + b2[0],
                               r0.w + r1.w + r2.w + r3.w + b2[1]);
    }
}

// ---------------- Kernel B: l[p] = sum_q 2^(f1[p].f2[q]*s); write {f1*s, V0/l, V1/l}
// block = (n, 16 p's); f1 block-uniform -> SGPRs; wave wid streams its q-quarter
// as float4 (2 q per entry), per-lane coalesced, stride 64 entries.
__global__ __launch_bounds__(256) void rowstats_kernel(
        const float2* __restrict__ f1v, const float2* __restrict__ f2v,
        const float* __restrict__ outv, float4* __restrict__ stats4) {
    __shared__ float red[4][16];
    int tid = threadIdx.x;
    int lane = tid & 63;
    int wid = tid >> 6;
    int b = blockIdx.x;                // 1024 blocks
    int n = b >> 8;
    int pg = (b & 255) << 4;           // 16 p's
    int base = n * HW;

    int ub = __builtin_amdgcn_readfirstlane(base + pg);
    float f10[16], f11[16];
#pragma unroll
    for (int j = 0; j < 16; ++j) {     // uniform -> s_load, lives in SGPRs
        float2 f1 = f1v[ub + j];
        f10[j] = f1.x * SCALE2;
        f11[j] = f1.y * SCALE2;
    }
    const float4* f2b = (const float4*)(f2v + base) + wid * 512 + lane;
    float acc[16];
#pragma unroll
    for (int j = 0; j < 16; ++j) acc[j] = 0.f;
    float4 cur = f2b[0];
#pragma unroll
    for (int s = 0; s < 8; ++s) {
        float4 nxt = f2b[((s + 1) & 7) * 64];   // distance-1 rotation, const offsets
#pragma unroll
        for (int j = 0; j < 16; ++j) {
            float e0 = exp2_raw(f10[j] * cur.x + f11[j] * cur.y);
            float e1 = exp2_raw(f10[j] * cur.z + f11[j] * cur.w);
            acc[j] += e0 + e1;
        }
        cur = nxt;
    }
#pragma unroll
    for (int j = 0; j < 16; ++j) {
        float a = acc[j];
        a += __shfl_xor(a, 1);  a += __shfl_xor(a, 2);
        a += __shfl_xor(a, 4);  a += __shfl_xor(a, 8);
        a += __shfl_xor(a, 16); a += __shfl_xor(a, 32);
        acc[j] = a;
    }
    if (lane == 0) {
#pragma unroll
        for (int j = 0; j < 16; ++j) red[wid][j] = acc[j];
    }
    __syncthreads();
    if (tid < 16) {
        float lt = red[0][tid] + red[1][tid] + red[2][tid] + red[3][tid];
        float inv = 1.0f / lt;
        int pp = pg + tid;
        float2 f1 = f1v[base + pp];
        float v0 = outv[(n * 2 + 0) * HW + pp];
        float v1 = outv[(n * 2 + 1) * HW + pp];
        stats4[base + pp] = make_float4(f1.x * SCALE2, f1.y * SCALE2, v0 * inv, v1 * inv);
    }
}

// ---------------- Kernel C: o[c,q] = sum_p (V[c,p]/l[p]) * 2^(f1[p].f2[q]*s)
// block = (n, 16 q's); f2-of-q block-uniform -> SGPRs; wave wid streams its
// p-quarter of stats4, per-lane coalesced, stride 64 entries.
__global__ __launch_bounds__(256) void colout_kernel(
        const float2* __restrict__ f2v, const float4* __restrict__ stats4,
        float* __restrict__ o) {
    __shared__ float red[4][16][2];
    int tid = threadIdx.x;
    int lane = tid & 63;
    int wid = tid >> 6;
    int b = blockIdx.x;                // 1024 blocks
    int n = b >> 8;
    int qg = (b & 255) << 4;           // 16 q's
    int base = n * HW;

    int ub = __builtin_amdgcn_readfirstlane(base + qg);
    float g0[16], g1[16];
#pragma unroll
    for (int j = 0; j < 16; ++j) {     // uniform -> s_load (SCALE2 folded in stats4)
        float2 f2 = f2v[ub + j];
        g0[j] = f2.x;
        g1[j] = f2.y;
    }
    const float4* stb = stats4 + base + wid * 1024 + lane;
    float o0[16], o1[16];
#pragma unroll
    for (int j = 0; j < 16; ++j) { o0[j] = 0.f; o1[j] = 0.f; }
    float4 cur = stb[0];
#pragma unroll
    for (int s = 0; s < 16; ++s) {
        float4 nxt = stb[((s + 1) & 15) * 64];  // distance-1 rotation, const offsets
#pragma unroll
        for (int j = 0; j < 16; ++j) {
            float e = exp2_raw(g0[j] * cur.x + g1[j] * cur.y);
            o0[j] += cur.z * e;
            o1[j] += cur.w * e;
        }
        cur = nxt;
    }
#pragma unroll
    for (int j = 0; j < 16; ++j) {
        float a = o0[j], c = o1[j];
        a += __shfl_xor(a, 1);  c += __shfl_xor(c, 1);
        a += __shfl_xor(a, 2);  c += __shfl_xor(c, 2);
        a += __shfl_xor(a, 4);  c += __shfl_xor(c, 4);
        a += __shfl_xor(a, 8);  c += __shfl_xor(c, 8);
        a += __shfl_xor(a, 16); c += __shfl_xor(c, 16);
        a += __shfl_xor(a, 32); c += __shfl_xor(c, 32);
        o0[j] = a; o1[j] = c;
    }
    if (lane == 0) {
#pragma unroll
        for (int j = 0; j < 16; ++j) { red[wid][j][0] = o0[j]; red[wid][j][1] = o1[j]; }
    }
    __syncthreads();
    if (tid < 32) {
        int qq = tid >> 1, c = tid & 1;
        float r = red[0][qq][c] + red[1][qq][c] + red[2][qq][c] + red[3][qq][c];
        o[(n * 2 + c) * HW + qg + qq] = r;
    }
}

extern "C" void kernel_launch(void* const* d_in, const int* in_sizes, int n_in,
                              void* d_out, int out_size, void* d_ws, size_t ws_size,
                              hipStream_t stream) {
    const float* feat = (const float*)d_in[0];   // (4,32,64,64)
    const float* outv = (const float*)d_in[1];   // (4,2,64,64)
    const float* w1   = (const float*)d_in[2];   // (2,32)
    const float* b1   = (const float*)d_in[3];   // (2,)
    const float* w2   = (const float*)d_in[4];   // (2,32)
    const float* b2   = (const float*)d_in[5];   // (2,)
    float* o = (float*)d_out;                    // (4,2,64,64)

    // workspace layout (512 KB used):
    float*  ws     = (float*)d_ws;
    float2* f1v    = (float2*)ws;                // 16384 float2 = 128 KB
    float2* f2v    = (float2*)(ws + 32768);      // 16384 float2 = 128 KB
    float4* stats4 = (float4*)(ws + 65536);      // 16384 float4 = 256 KB

    proj_kernel<<<256, 256, 0, stream>>>(feat, w1, b1, w2, b2, f1v, f2v);
    rowstats_kernel<<<1024, 256, 0, stream>>>(f1v, f2v, outv, stats4);
    colout_kernel<<<1024, 256, 0, stream>>>(f2v, stats4, o);
}